// Round 17
// baseline (167.847 us; speedup 1.0000x reference)
//
#include <hip/hip_runtime.h>
#include <hip/hip_bf16.h>

#define SEQ 4096
#define BATCH 2
#define DMODEL 1024
#define NH 16
#define HDIM 64
#define NEGM (-1.0e30f)
#define NT 16  // DMODEL / BK(=64)

typedef __attribute__((ext_vector_type(8))) short bf16x8;
typedef __attribute__((ext_vector_type(8))) unsigned short us8;
typedef __attribute__((ext_vector_type(4))) unsigned short us4;
typedef __attribute__((ext_vector_type(4))) float f32x4;

__device__ __forceinline__ unsigned short f2bf(float f) {
    union { float f; unsigned u; } v; v.f = f;
    unsigned u = v.u;
    return (unsigned short)((u + 0x7fffu + ((u >> 16) & 1u)) >> 16);
}

__device__ __forceinline__ unsigned packbf(float a, float b) {
    return (unsigned)f2bf(a) | ((unsigned)f2bf(b) << 16);
}

// async global->LDS, 16B per lane; LDS dest wave-uniform base (HW adds lane*16)
#define GL16(g, l)                                                              \
    __builtin_amdgcn_global_load_lds(                                           \
        (const __attribute__((address_space(1))) unsigned int*)(g),             \
        (__attribute__((address_space(3))) unsigned int*)(l), 16, 0, 0)

// ------- ONE fused prep kernel -------
__global__ __launch_bounds__(256) void prep_all(const float* __restrict__ Wq,
                                                const float* __restrict__ Wk,
                                                const float* __restrict__ Wv,
                                                const float* __restrict__ Wo,
                                                const float* __restrict__ query,
                                                const float* __restrict__ bq,
                                                const float* __restrict__ bk,
                                                const float* __restrict__ bv,
                                                unsigned short* __restrict__ wcat,
                                                unsigned short* __restrict__ wot,
                                                unsigned short* __restrict__ xb,
                                                float* __restrict__ bcat) {
    __shared__ float tile[64][65];
    const int bid = blockIdx.x;
    const int tid = threadIdx.x;
    if (bid < 1024) {
        const int z = bid >> 8, by = (bid >> 4) & 15, bx = bid & 15;
        const float* W = (z == 0) ? Wq : (z == 1) ? Wk : (z == 2) ? Wv : Wo;
        unsigned short* Wt = (z == 3) ? wot : wcat + (size_t)z * 1024 * 1024;
        const float scale = (z == 0) ? 0.125f : 1.0f;
        const int n0 = bx * 64, k0 = by * 64;
        const int tx = tid & 63, ty = tid >> 6;
        for (int dy = ty; dy < 64; dy += 4)
            tile[dy][tx] = W[(size_t)(k0 + dy) * DMODEL + n0 + tx];
        __syncthreads();
        for (int dy = ty; dy < 64; dy += 4)
            Wt[(size_t)(n0 + dy) * DMODEL + k0 + tx] = f2bf(tile[tx][dy] * scale);
    } else if (bid < 9216) {
        int t = (bid - 1024) * 256 + tid;
        int d4 = (t & 255) * 4;
        int row = t >> 8;
        int b = row >> 12, s = row & (SEQ - 1);
        float4 v = *(const float4*)(query + ((size_t)s * BATCH + b) * DMODEL + d4);
        us4 o;
        o[0] = f2bf(v.x); o[1] = f2bf(v.y); o[2] = f2bf(v.z); o[3] = f2bf(v.w);
        *(us4*)(xb + (size_t)row * DMODEL + d4) = o;
    } else {
        int i = (bid - 9216) * 256 + tid;  // 0..3071
        float v;
        if (i < 1024) v = bq[i] * 0.125f;
        else if (i < 2048) v = bk[i - 1024];
        else v = bv[i - 2048];
        bcat[i] = v;
    }
}

// ---- MODE-0 store helper ----
__device__ __forceinline__ void store_qkv(float v0, float v1, float v2, float v3,
                                          int row0, int col, float bval,
                                          unsigned short* __restrict__ qb,
                                          unsigned short* __restrict__ kb,
                                          unsigned short* __restrict__ vtb) {
    const int proj = col >> 10;
    const int ch = col & 1023;
    const int h = ch >> 6, hd = ch & 63;
    float vv[4] = {v0, v1, v2, v3};
    if (proj == 2) {
        const int b = row0 >> 12, s = row0 & (SEQ - 1);
        us4 o;
#pragma unroll
        for (int r = 0; r < 4; ++r) o[r] = f2bf(vv[r] + bval);
        *(us4*)(vtb + ((size_t)(b * NH + h) * HDIM + hd) * SEQ + s) = o;
    } else {
        unsigned short* dst = (proj == 0) ? qb : kb;
#pragma unroll
        for (int r = 0; r < 4; ++r) {
            const int row = row0 + r;
            const int b = row >> 12, s = row & (SEQ - 1);
            dst[((size_t)(b * NH + h) * SEQ + s) * HDIM + hd] = f2bf(vv[r] + bval);
        }
    }
}

// ------- 256x192 GEMM (QKV projection), BK=64, dbuf, stage-at-top, 1 barrier/tile ----
// 8 waves as 4M x 2N (wave = 64x96).
__global__ __launch_bounds__(512) void gemm192(const unsigned short* __restrict__ A,
                                               const unsigned short* __restrict__ Bt,
                                               const float* __restrict__ bias,
                                               unsigned short* __restrict__ qb,
                                               unsigned short* __restrict__ kb,
                                               unsigned short* __restrict__ vtb) {
    __shared__ __align__(16) unsigned short lds[57344];  // 2 x (A 16384 + B 12288)
    const int tid = threadIdx.x;
    const int lane = tid & 63, wid = tid >> 6;
    const int lr = lane & 15, lg = lane >> 4;
    const int wm = wid >> 1, wn = wid & 1;   // 4M x 2N
    const int cpx = (int)gridDim.x >> 3;
    const int orig = ((int)blockIdx.x & 7) * cpx + ((int)blockIdx.x >> 3);
    const int m0 = (orig >> 4) * 256;     // 32 m-blocks
    const int n0 = (orig & 15) * 192;     // 16 n-blocks

    const int srow = wid * 8 + (lane >> 3);
    const int scol = ((lane & 7) ^ (lane >> 3)) << 3;

    f32x4 acc[4][6];
#pragma unroll
    for (int m = 0; m < 4; ++m)
#pragma unroll
        for (int n = 0; n < 6; ++n) {
            f32x4 z = {0.f, 0.f, 0.f, 0.f};
            acc[m][n] = z;
        }

    const unsigned short* gA = A + (size_t)(m0 + srow) * DMODEL + scol;
    const unsigned short* gB = Bt + (size_t)(n0 + srow) * DMODEL + scol;

#define STAGE192(kt, bsel)                                                       \
    do {                                                                         \
        const unsigned short* ga_ = gA + (kt) * 64;                              \
        unsigned short* la_ = &lds[(bsel) * 28672 + wid * 512];                  \
        _Pragma("unroll")                                                        \
        for (int r_ = 0; r_ < 4; ++r_)                                           \
            GL16(ga_ + (size_t)r_ * 64 * DMODEL, la_ + r_ * 4096);               \
        const unsigned short* gb_ = gB + (kt) * 64;                              \
        unsigned short* lb_ = &lds[(bsel) * 28672 + 16384 + wid * 512];          \
        _Pragma("unroll")                                                        \
        for (int r_ = 0; r_ < 3; ++r_)                                           \
            GL16(gb_ + (size_t)r_ * 64 * DMODEL, lb_ + r_ * 4096);               \
    } while (0)

    STAGE192(0, 0);
    asm volatile("s_waitcnt vmcnt(0)" ::: "memory");
    __builtin_amdgcn_s_barrier();
    asm volatile("" ::: "memory");

    const int swz = (lr & 7) << 3;
    for (int t = 0; t < NT; ++t) {
        if (t + 1 < NT) STAGE192(t + 1, (t + 1) & 1);
        const unsigned short* Ab = &lds[(t & 1) * 28672];
        const unsigned short* Bb = Ab + 16384;
#pragma unroll
        for (int ks = 0; ks < 2; ++ks) {
            const int kc = (ks * 32 + lg * 8) ^ swz;
            bf16x8 af[4], bfr[6];
#pragma unroll
            for (int fm = 0; fm < 4; ++fm)
                af[fm] = *(const bf16x8*)&Ab[(wm * 64 + fm * 16 + lr) * 64 + kc];
#pragma unroll
            for (int fn = 0; fn < 6; ++fn)
                bfr[fn] = *(const bf16x8*)&Bb[(wn * 96 + fn * 16 + lr) * 64 + kc];
            __builtin_amdgcn_s_setprio(1);
#pragma unroll
            for (int fm = 0; fm < 4; ++fm)
#pragma unroll
                for (int fn = 0; fn < 6; ++fn)
                    acc[fm][fn] = __builtin_amdgcn_mfma_f32_16x16x32_bf16(af[fm], bfr[fn], acc[fm][fn], 0, 0, 0);
            __builtin_amdgcn_s_setprio(0);
        }
        __builtin_amdgcn_sched_barrier(0);
        asm volatile("s_waitcnt lgkmcnt(0)" ::: "memory");
        asm volatile("s_waitcnt vmcnt(0)" ::: "memory");
        __builtin_amdgcn_s_barrier();
        asm volatile("" ::: "memory");
    }
#undef STAGE192

#pragma unroll
    for (int fn = 0; fn < 6; ++fn) {
        const int col = n0 + wn * 96 + fn * 16 + lr;
        const float bval = bias[col];
#pragma unroll
        for (int fm = 0; fm < 4; ++fm) {
            const int row0 = m0 + wm * 64 + fm * 16 + lg * 4;
            store_qkv(acc[fm][fn][0], acc[fm][fn][1], acc[fm][fn][2], acc[fm][fn][3],
                      row0, col, bval, qb, kb, vtb);
        }
    }
}

// ------- 128x128 GEMM (output proj), BK=64, single 32KB buffer, 4 blocks/CU ----
__global__ __launch_bounds__(256, 4) void gemm128o(const unsigned short* __restrict__ A,
                                                   const unsigned short* __restrict__ Bt,
                                                   const float* __restrict__ bias,
                                                   float* __restrict__ out) {
    __shared__ __align__(16) unsigned short lds[16384];  // A 8192 + B 8192 elems
    const int tid = threadIdx.x;
    const int lane = tid & 63, wid = tid >> 6;   // 4 waves
    const int lr = lane & 15, lg = lane >> 4;
    const int wm = wid >> 1, wn = wid & 1;
    const int cpx = (int)gridDim.x >> 3;
    const int orig = ((int)blockIdx.x & 7) * cpx + ((int)blockIdx.x >> 3);
    const int m0 = (orig >> 3) * 128;    // 64 m-blocks
    const int n0 = (orig & 7) * 128;     // 8 n-blocks

    const int srow = wid * 8 + (lane >> 3);               // 0..31 (+r*32)
    const int scol = ((lane & 7) ^ (lane >> 3)) << 3;

    f32x4 acc[4][4];
#pragma unroll
    for (int m = 0; m < 4; ++m)
#pragma unroll
        for (int n = 0; n < 4; ++n) {
            f32x4 z = {0.f, 0.f, 0.f, 0.f};
            acc[m][n] = z;
        }

    const unsigned short* gA = A + (size_t)(m0 + srow) * DMODEL + scol;
    const unsigned short* gB = Bt + (size_t)(n0 + srow) * DMODEL + scol;
    const int swz = (lr & 7) << 3;

    for (int t = 0; t < NT; ++t) {
        {
            const unsigned short* ga_ = gA + t * 64;
            unsigned short* la_ = &lds[wid * 512];
#pragma unroll
            for (int r_ = 0; r_ < 4; ++r_)
                GL16(ga_ + (size_t)r_ * 32 * DMODEL, la_ + r_ * 2048);
            const unsigned short* gb_ = gB + t * 64;
            unsigned short* lb_ = &lds[8192 + wid * 512];
#pragma unroll
            for (int r_ = 0; r_ < 4; ++r_)
                GL16(gb_ + (size_t)r_ * 32 * DMODEL, lb_ + r_ * 2048);
        }
        asm volatile("s_waitcnt vmcnt(0)" ::: "memory");
        __builtin_amdgcn_s_barrier();
        asm volatile("" ::: "memory");
#pragma unroll
        for (int ks = 0; ks < 2; ++ks) {
            const int kc = (ks * 32 + lg * 8) ^ swz;
            bf16x8 af[4], bfr[4];
#pragma unroll
            for (int fm = 0; fm < 4; ++fm)
                af[fm] = *(const bf16x8*)&lds[(wm * 64 + fm * 16 + lr) * 64 + kc];
#pragma unroll
            for (int fn = 0; fn < 4; ++fn)
                bfr[fn] = *(const bf16x8*)&lds[8192 + (wn * 64 + fn * 16 + lr) * 64 + kc];
            __builtin_amdgcn_s_setprio(1);
#pragma unroll
            for (int fm = 0; fm < 4; ++fm)
#pragma unroll
                for (int fn = 0; fn < 4; ++fn)
                    acc[fm][fn] = __builtin_amdgcn_mfma_f32_16x16x32_bf16(af[fm], bfr[fn], acc[fm][fn], 0, 0, 0);
            __builtin_amdgcn_s_setprio(0);
        }
        __builtin_amdgcn_sched_barrier(0);
        asm volatile("s_waitcnt lgkmcnt(0)" ::: "memory");
        __builtin_amdgcn_s_barrier();
        asm volatile("" ::: "memory");
    }

#pragma unroll
    for (int fn = 0; fn < 4; ++fn) {
        const int col = n0 + wn * 64 + fn * 16 + lr;
        const float bval = bias[col];
#pragma unroll
        for (int fm = 0; fm < 4; ++fm) {
            const int row0 = m0 + wm * 64 + fm * 16 + lg * 4;
#pragma unroll
            for (int r = 0; r < 4; ++r) {
                const int row = row0 + r;
                const int b = row >> 12, s = row & (SEQ - 1);
                out[((size_t)s * BATCH + b) * DMODEL + col] = acc[fm][fn][r] + bval;
            }
        }
    }
}

// ---------------- banded flash attention: swapped-QK, no P LDS round-trip ----------------
// Same algorithm as R15 (numerically verified there), but WITHOUT the (512,8)
// launch bound that forced VGPR=32 and spilled to scratch. Natural allocation
// (~75-85 VGPR) -> ~6 waves/SIMD, no spills. LDS only 18.4 KB.
__global__ __launch_bounds__(512) void attn_kernel(const unsigned short* __restrict__ qb,
                                                   const unsigned short* __restrict__ kb,
                                                   const unsigned short* __restrict__ vtb,
                                                   unsigned short* __restrict__ ao) {
    __shared__ __align__(16) unsigned short Ks[64][72];    // [key][hd]  (+8 pad)
    __shared__ __align__(16) unsigned short Vs[64][72];    // [hd][key]  (+8 pad)
    const int tid = threadIdx.x;
    const int lane = tid & 63, wid = tid >> 6;
    const int lr = lane & 15, lg = lane >> 4;
    const int blk = ((int)blockIdx.x & 7) * 128 + ((int)blockIdx.x >> 3);
    const int qc = blk & 31, h = (blk >> 5) & 15, b = blk >> 9;
    const int q0 = qc * 128;
    const unsigned short* Qh = qb + (size_t)(b * NH + h) * SEQ * HDIM;
    const unsigned short* Kh = kb + (size_t)(b * NH + h) * SEQ * HDIM;
    const unsigned short* Vh = vtb + (size_t)(b * NH + h) * HDIM * SEQ;
    const int qw = q0 + wid * 16;
    const int qpos = qw + lr;        // this lane's query row (swapped layout)
    const int odd = lg & 1;

    bf16x8 qf0 = *(const bf16x8*)(Qh + (size_t)(qw + lr) * HDIM + lg * 8);
    bf16x8 qf1 = *(const bf16x8*)(Qh + (size_t)(qw + lr) * HDIM + 32 + lg * 8);

    f32x4 oacc[4];
    float lsum = 0.f;
#pragma unroll
    for (int n = 0; n < 4; ++n) {
        f32x4 z = {0.f, 0.f, 0.f, 0.f};
        oacc[n] = z;
    }

    int lo = q0 - 256; if (lo < 0) lo = 0;
    int hi = q0 + 384; if (hi > SEQ) hi = SEQ;

    const int srow = tid >> 3, sseg = (tid & 7) * 8;  // 64 rows x 8 x 16B

    us8 kpre = *(const us8*)(Kh + (size_t)(lo + srow) * HDIM + sseg);
    us8 vpre = *(const us8*)(Vh + (size_t)srow * SEQ + lo + sseg);

    for (int kt = lo; kt < hi; kt += 64) {
        __syncthreads();
        *(us8*)&Ks[srow][sseg] = kpre;
        *(us8*)&Vs[srow][sseg] = vpre;
        if (kt + 64 < hi) {
            kpre = *(const us8*)(Kh + (size_t)(kt + 64 + srow) * HDIM + sseg);
            vpre = *(const us8*)(Vh + (size_t)srow * SEQ + kt + 64 + sseg);
        }
        __builtin_amdgcn_sched_barrier(0);
        __syncthreads();

        const bool full = (kt >= qw - 241) && (kt + 63 <= qw + 256);
#pragma unroll
        for (int ks = 0; ks < 2; ++ks) {
            unsigned gdw[2][4];
#pragma unroll
            for (int bi = 0; bi < 2; ++bi) {
                const int n = ks * 2 + bi;
                bf16x8 kf0 = *(const bf16x8*)&Ks[n * 16 + lr][lg * 8];
                bf16x8 kf1 = *(const bf16x8*)&Ks[n * 16 + lr][32 + lg * 8];
                f32x4 z = {0.f, 0.f, 0.f, 0.f};
                __builtin_amdgcn_s_setprio(1);
                f32x4 sf = __builtin_amdgcn_mfma_f32_16x16x32_bf16(kf0, qf0, z, 0, 0, 0);
                sf = __builtin_amdgcn_mfma_f32_16x16x32_bf16(kf1, qf1, sf, 0, 0, 0);
                __builtin_amdgcn_s_setprio(0);
                if (!full) {
#pragma unroll
                    for (int r = 0; r < 4; ++r) {
                        const int kpos = kt + n * 16 + lg * 4 + r;
                        if (kpos < qpos - 256 || kpos > qpos + 256) sf[r] = NEGM;
                    }
                }
                const float p0 = __expf(sf[0]);
                const float p1 = __expf(sf[1]);
                const float p2 = __expf(sf[2]);
                const float p3 = __expf(sf[3]);
                lsum += (p0 + p1) + (p2 + p3);
                const unsigned dA = packbf(p0, p1);
                const unsigned dB = packbf(p2, p3);
                const unsigned rA = __shfl_xor((int)dA, 16, 64);
                const unsigned rB = __shfl_xor((int)dB, 16, 64);
                gdw[bi][0] = odd ? rA : dA;
                gdw[bi][1] = odd ? rB : dB;
                gdw[bi][2] = odd ? dA : rA;
                gdw[bi][3] = odd ? dB : rB;
            }
            union { unsigned u[4]; bf16x8 v; } pu;
#pragma unroll
            for (int j = 0; j < 4; ++j) pu.u[j] = odd ? gdw[1][j] : gdw[0][j];
            const int koff = (ks * 2 + odd) * 16 + (lg >> 1) * 8;
            __builtin_amdgcn_s_setprio(1);
#pragma unroll
            for (int n = 0; n < 4; ++n) {
                bf16x8 vf = *(const bf16x8*)&Vs[n * 16 + lr][koff];
                oacc[n] = __builtin_amdgcn_mfma_f32_16x16x32_bf16(pu.v, vf, oacc[n], 0, 0, 0);
            }
            __builtin_amdgcn_s_setprio(0);
        }
    }

    // reduce lsum over the 4 lg-copies of each q (lanes lr+16*lg)
    lsum += __shfl_xor(lsum, 16, 64);
    lsum += __shfl_xor(lsum, 32, 64);
    // redistribute: output rows are q = qw + lg*4 + r; totals live at lane (lr=q_local)
    float ls[4];
#pragma unroll
    for (int r = 0; r < 4; ++r) ls[r] = __shfl(lsum, lg * 4 + r, 64);

#pragma unroll
    for (int n = 0; n < 4; ++n)
#pragma unroll
        for (int r = 0; r < 4; ++r) {
            const int row = qw + lg * 4 + r;
            const float o = oacc[n][r] / ls[r];
            ao[((size_t)b * SEQ + row) * DMODEL + h * HDIM + n * 16 + lr] = f2bf(o);
        }
}

extern "C" void kernel_launch(void* const* d_in, const int* in_sizes, int n_in,
                              void* d_out, int out_size, void* d_ws, size_t ws_size,
                              hipStream_t stream) {
    (void)in_sizes; (void)n_in; (void)out_size; (void)ws_size;
    const float* query = (const float*)d_in[0];
    const float* Wq = (const float*)d_in[1];
    const float* bq = (const float*)d_in[2];
    const float* Wk = (const float*)d_in[3];
    const float* bk = (const float*)d_in[4];
    const float* Wv = (const float*)d_in[5];
    const float* bv = (const float*)d_in[6];
    const float* Wo = (const float*)d_in[7];
    const float* bo = (const float*)d_in[8];
    float* out = (float*)d_out;

    char* ws = (char*)d_ws;
    unsigned short* xb   = (unsigned short*)ws;                       // 16MB (reused as ao)
    unsigned short* wcat = (unsigned short*)(ws + (16ull << 20));     // 6MB
    unsigned short* wot  = (unsigned short*)(ws + (22ull << 20));     // 2MB
    float*          bcat = (float*)(ws + (24ull << 20));              // 12KB
    unsigned short* qb   = (unsigned short*)(ws + (25ull << 20));     // 16MB
    unsigned short* kb   = (unsigned short*)(ws + (41ull << 20));     // 16MB
    unsigned short* vtb  = (unsigned short*)(ws + (57ull << 20));     // 16MB
    unsigned short* ao   = xb;

    prep_all<<<9228, 256, 0, stream>>>(Wq, Wk, Wv, Wo, query, bq, bk, bv,
                                       wcat, wot, xb, bcat);
    gemm192<<<512, 512, 0, stream>>>(xb, wcat, bcat, qb, kb, vtb);
    attn_kernel<<<1024, 512, 0, stream>>>(qb, kb, vtb, ao);
    gemm128o<<<512, 256, 0, stream>>>(ao, wot, bo, out);
}

// Round 18
// 140.476 us; speedup vs baseline: 1.1948x; 1.1948x over previous
//
#include <hip/hip_runtime.h>
#include <hip/hip_bf16.h>

#define SEQ 4096
#define BATCH 2
#define DMODEL 1024
#define NH 16
#define HDIM 64
#define NEGM (-1.0e30f)
#define NT 16  // DMODEL / BK(=64)

typedef __attribute__((ext_vector_type(8))) short bf16x8;
typedef __attribute__((ext_vector_type(8))) unsigned short us8;
typedef __attribute__((ext_vector_type(4))) unsigned short us4;
typedef __attribute__((ext_vector_type(4))) float f32x4;

__device__ __forceinline__ unsigned short f2bf(float f) {
    union { float f; unsigned u; } v; v.f = f;
    unsigned u = v.u;
    return (unsigned short)((u + 0x7fffu + ((u >> 16) & 1u)) >> 16);
}

// async global->LDS, 16B per lane; LDS dest wave-uniform base (HW adds lane*16)
#define GL16(g, l)                                                              \
    __builtin_amdgcn_global_load_lds(                                           \
        (const __attribute__((address_space(1))) unsigned int*)(g),             \
        (__attribute__((address_space(3))) unsigned int*)(l), 16, 0, 0)

// ------- ONE fused prep kernel -------
// bid 0..1023:    weight transpose (z = bid>>8 -> {Wq*0.125, Wk, Wv, Wo})
// bid 1024..9215: convert query -> xb bf16 (b,s,d)
// bid 9216..9227: build bcat
__global__ __launch_bounds__(256) void prep_all(const float* __restrict__ Wq,
                                                const float* __restrict__ Wk,
                                                const float* __restrict__ Wv,
                                                const float* __restrict__ Wo,
                                                const float* __restrict__ query,
                                                const float* __restrict__ bq,
                                                const float* __restrict__ bk,
                                                const float* __restrict__ bv,
                                                unsigned short* __restrict__ wcat,
                                                unsigned short* __restrict__ wot,
                                                unsigned short* __restrict__ xb,
                                                float* __restrict__ bcat) {
    __shared__ float tile[64][65];
    const int bid = blockIdx.x;
    const int tid = threadIdx.x;
    if (bid < 1024) {
        const int z = bid >> 8, by = (bid >> 4) & 15, bx = bid & 15;
        const float* W = (z == 0) ? Wq : (z == 1) ? Wk : (z == 2) ? Wv : Wo;
        unsigned short* Wt = (z == 3) ? wot : wcat + (size_t)z * 1024 * 1024;
        const float scale = (z == 0) ? 0.125f : 1.0f;
        const int n0 = bx * 64, k0 = by * 64;
        const int tx = tid & 63, ty = tid >> 6;
        for (int dy = ty; dy < 64; dy += 4)
            tile[dy][tx] = W[(size_t)(k0 + dy) * DMODEL + n0 + tx];
        __syncthreads();
        for (int dy = ty; dy < 64; dy += 4)
            Wt[(size_t)(n0 + dy) * DMODEL + k0 + tx] = f2bf(tile[tx][dy] * scale);
    } else if (bid < 9216) {
        int t = (bid - 1024) * 256 + tid;
        int d4 = (t & 255) * 4;
        int row = t >> 8;
        int b = row >> 12, s = row & (SEQ - 1);
        float4 v = *(const float4*)(query + ((size_t)s * BATCH + b) * DMODEL + d4);
        us4 o;
        o[0] = f2bf(v.x); o[1] = f2bf(v.y); o[2] = f2bf(v.z); o[3] = f2bf(v.w);
        *(us4*)(xb + (size_t)row * DMODEL + d4) = o;
    } else {
        int i = (bid - 9216) * 256 + tid;  // 0..3071
        float v;
        if (i < 1024) v = bq[i] * 0.125f;
        else if (i < 2048) v = bk[i - 1024];
        else v = bv[i - 2048];
        bcat[i] = v;
    }
}

// ---- MODE-0 store helper ----
__device__ __forceinline__ void store_qkv(float v0, float v1, float v2, float v3,
                                          int row0, int col, float bval,
                                          unsigned short* __restrict__ qb,
                                          unsigned short* __restrict__ kb,
                                          unsigned short* __restrict__ vtb) {
    const int proj = col >> 10;
    const int ch = col & 1023;
    const int h = ch >> 6, hd = ch & 63;
    float vv[4] = {v0, v1, v2, v3};
    if (proj == 2) {
        const int b = row0 >> 12, s = row0 & (SEQ - 1);
        us4 o;
#pragma unroll
        for (int r = 0; r < 4; ++r) o[r] = f2bf(vv[r] + bval);
        *(us4*)(vtb + ((size_t)(b * NH + h) * HDIM + hd) * SEQ + s) = o;
    } else {
        unsigned short* dst = (proj == 0) ? qb : kb;
#pragma unroll
        for (int r = 0; r < 4; ++r) {
            const int row = row0 + r;
            const int b = row >> 12, s = row & (SEQ - 1);
            dst[((size_t)(b * NH + h) * SEQ + s) * HDIM + hd] = f2bf(vv[r] + bval);
        }
    }
}

// ------- 256x192 GEMM (QKV projection), BK=64, dbuf, stage-at-top, 1 barrier/tile ----
// 8 waves as 4M x 2N (wave = 64x96).
__global__ __launch_bounds__(512) void gemm192(const unsigned short* __restrict__ A,
                                               const unsigned short* __restrict__ Bt,
                                               const float* __restrict__ bias,
                                               unsigned short* __restrict__ qb,
                                               unsigned short* __restrict__ kb,
                                               unsigned short* __restrict__ vtb) {
    __shared__ __align__(16) unsigned short lds[57344];  // 2 x (A 16384 + B 12288)
    const int tid = threadIdx.x;
    const int lane = tid & 63, wid = tid >> 6;
    const int lr = lane & 15, lg = lane >> 4;
    const int wm = wid >> 1, wn = wid & 1;   // 4M x 2N
    const int cpx = (int)gridDim.x >> 3;
    const int orig = ((int)blockIdx.x & 7) * cpx + ((int)blockIdx.x >> 3);
    const int m0 = (orig >> 4) * 256;     // 32 m-blocks
    const int n0 = (orig & 15) * 192;     // 16 n-blocks

    const int srow = wid * 8 + (lane >> 3);
    const int scol = ((lane & 7) ^ (lane >> 3)) << 3;

    f32x4 acc[4][6];
#pragma unroll
    for (int m = 0; m < 4; ++m)
#pragma unroll
        for (int n = 0; n < 6; ++n) {
            f32x4 z = {0.f, 0.f, 0.f, 0.f};
            acc[m][n] = z;
        }

    const unsigned short* gA = A + (size_t)(m0 + srow) * DMODEL + scol;
    const unsigned short* gB = Bt + (size_t)(n0 + srow) * DMODEL + scol;

#define STAGE192(kt, bsel)                                                       \
    do {                                                                         \
        const unsigned short* ga_ = gA + (kt) * 64;                              \
        unsigned short* la_ = &lds[(bsel) * 28672 + wid * 512];                  \
        _Pragma("unroll")                                                        \
        for (int r_ = 0; r_ < 4; ++r_)                                           \
            GL16(ga_ + (size_t)r_ * 64 * DMODEL, la_ + r_ * 4096);               \
        const unsigned short* gb_ = gB + (kt) * 64;                              \
        unsigned short* lb_ = &lds[(bsel) * 28672 + 16384 + wid * 512];          \
        _Pragma("unroll")                                                        \
        for (int r_ = 0; r_ < 3; ++r_)                                           \
            GL16(gb_ + (size_t)r_ * 64 * DMODEL, lb_ + r_ * 4096);               \
    } while (0)

    STAGE192(0, 0);
    asm volatile("s_waitcnt vmcnt(0)" ::: "memory");
    __builtin_amdgcn_s_barrier();
    asm volatile("" ::: "memory");

    const int swz = (lr & 7) << 3;
    for (int t = 0; t < NT; ++t) {
        if (t + 1 < NT) STAGE192(t + 1, (t + 1) & 1);
        const unsigned short* Ab = &lds[(t & 1) * 28672];
        const unsigned short* Bb = Ab + 16384;
#pragma unroll
        for (int ks = 0; ks < 2; ++ks) {
            const int kc = (ks * 32 + lg * 8) ^ swz;
            bf16x8 af[4], bfr[6];
#pragma unroll
            for (int fm = 0; fm < 4; ++fm)
                af[fm] = *(const bf16x8*)&Ab[(wm * 64 + fm * 16 + lr) * 64 + kc];
#pragma unroll
            for (int fn = 0; fn < 6; ++fn)
                bfr[fn] = *(const bf16x8*)&Bb[(wn * 96 + fn * 16 + lr) * 64 + kc];
            __builtin_amdgcn_s_setprio(1);
#pragma unroll
            for (int fm = 0; fm < 4; ++fm)
#pragma unroll
                for (int fn = 0; fn < 6; ++fn)
                    acc[fm][fn] = __builtin_amdgcn_mfma_f32_16x16x32_bf16(af[fm], bfr[fn], acc[fm][fn], 0, 0, 0);
            __builtin_amdgcn_s_setprio(0);
        }
        __builtin_amdgcn_sched_barrier(0);
        asm volatile("s_waitcnt lgkmcnt(0)" ::: "memory");
        asm volatile("s_waitcnt vmcnt(0)" ::: "memory");
        __builtin_amdgcn_s_barrier();
        asm volatile("" ::: "memory");
    }
#undef STAGE192

#pragma unroll
    for (int fn = 0; fn < 6; ++fn) {
        const int col = n0 + wn * 96 + fn * 16 + lr;
        const float bval = bias[col];
#pragma unroll
        for (int fm = 0; fm < 4; ++fm) {
            const int row0 = m0 + wm * 64 + fm * 16 + lg * 4;
            store_qkv(acc[fm][fn][0], acc[fm][fn][1], acc[fm][fn][2], acc[fm][fn][3],
                      row0, col, bval, qb, kb, vtb);
        }
    }
}

// ------- 128x128 GEMM (output proj), BK=64, single 32KB buffer, 4 blocks/CU ----
__global__ __launch_bounds__(256, 4) void gemm128o(const unsigned short* __restrict__ A,
                                                   const unsigned short* __restrict__ Bt,
                                                   const float* __restrict__ bias,
                                                   float* __restrict__ out) {
    __shared__ __align__(16) unsigned short lds[16384];  // A 8192 + B 8192 elems
    const int tid = threadIdx.x;
    const int lane = tid & 63, wid = tid >> 6;   // 4 waves
    const int lr = lane & 15, lg = lane >> 4;
    const int wm = wid >> 1, wn = wid & 1;
    const int cpx = (int)gridDim.x >> 3;
    const int orig = ((int)blockIdx.x & 7) * cpx + ((int)blockIdx.x >> 3);
    const int m0 = (orig >> 3) * 128;    // 64 m-blocks
    const int n0 = (orig & 7) * 128;     // 8 n-blocks

    const int srow = wid * 8 + (lane >> 3);               // 0..31 (+r*32)
    const int scol = ((lane & 7) ^ (lane >> 3)) << 3;

    f32x4 acc[4][4];
#pragma unroll
    for (int m = 0; m < 4; ++m)
#pragma unroll
        for (int n = 0; n < 4; ++n) {
            f32x4 z = {0.f, 0.f, 0.f, 0.f};
            acc[m][n] = z;
        }

    const unsigned short* gA = A + (size_t)(m0 + srow) * DMODEL + scol;
    const unsigned short* gB = Bt + (size_t)(n0 + srow) * DMODEL + scol;
    const int swz = (lr & 7) << 3;

    for (int t = 0; t < NT; ++t) {
        {
            const unsigned short* ga_ = gA + t * 64;
            unsigned short* la_ = &lds[wid * 512];
#pragma unroll
            for (int r_ = 0; r_ < 4; ++r_)
                GL16(ga_ + (size_t)r_ * 32 * DMODEL, la_ + r_ * 2048);
            const unsigned short* gb_ = gB + t * 64;
            unsigned short* lb_ = &lds[8192 + wid * 512];
#pragma unroll
            for (int r_ = 0; r_ < 4; ++r_)
                GL16(gb_ + (size_t)r_ * 32 * DMODEL, lb_ + r_ * 2048);
        }
        asm volatile("s_waitcnt vmcnt(0)" ::: "memory");
        __builtin_amdgcn_s_barrier();
        asm volatile("" ::: "memory");
#pragma unroll
        for (int ks = 0; ks < 2; ++ks) {
            const int kc = (ks * 32 + lg * 8) ^ swz;
            bf16x8 af[4], bfr[4];
#pragma unroll
            for (int fm = 0; fm < 4; ++fm)
                af[fm] = *(const bf16x8*)&lds[(wm * 64 + fm * 16 + lr) * 64 + kc];
#pragma unroll
            for (int fn = 0; fn < 4; ++fn)
                bfr[fn] = *(const bf16x8*)&lds[8192 + (wn * 64 + fn * 16 + lr) * 64 + kc];
            __builtin_amdgcn_s_setprio(1);
#pragma unroll
            for (int fm = 0; fm < 4; ++fm)
#pragma unroll
                for (int fn = 0; fn < 4; ++fn)
                    acc[fm][fn] = __builtin_amdgcn_mfma_f32_16x16x32_bf16(af[fm], bfr[fn], acc[fm][fn], 0, 0, 0);
            __builtin_amdgcn_s_setprio(0);
        }
        __builtin_amdgcn_sched_barrier(0);
        asm volatile("s_waitcnt lgkmcnt(0)" ::: "memory");
        __builtin_amdgcn_s_barrier();
        asm volatile("" ::: "memory");
    }

#pragma unroll
    for (int fn = 0; fn < 4; ++fn) {
        const int col = n0 + wn * 64 + fn * 16 + lr;
        const float bval = bias[col];
#pragma unroll
        for (int fm = 0; fm < 4; ++fm) {
            const int row0 = m0 + wm * 64 + fm * 16 + lg * 4;
#pragma unroll
            for (int r = 0; r < 4; ++r) {
                const int row = row0 + r;
                const int b = row >> 12, s = row & (SEQ - 1);
                out[((size_t)s * BATCH + b) * DMODEL + col] = acc[fm][fn][r] + bval;
            }
        }
    }
}

// ---------------- banded flash attention (round-7 version: 32 waves/CU) ----------------
// QBLK=128 (8 waves x 16 q-rows), KVBLK=64, fixed-max softmax, K/V reg-prefetch.
__global__ __launch_bounds__(512) void attn_kernel(const unsigned short* __restrict__ qb,
                                                   const unsigned short* __restrict__ kb,
                                                   const unsigned short* __restrict__ vtb,
                                                   unsigned short* __restrict__ ao) {
    __shared__ __align__(16) unsigned short Ks[64][72];    // [key][hd]   (+8 pad)
    __shared__ __align__(16) unsigned short Vs[64][72];    // [hd][key]   (+8 pad)
    __shared__ __align__(16) unsigned short Ps[8][16][72]; // per-wave [q][key] (+8 pad)
    const int tid = threadIdx.x;
    const int lane = tid & 63, wid = tid >> 6;
    const int lr = lane & 15, lg = lane >> 4;
    const int blk = ((int)blockIdx.x & 7) * 128 + ((int)blockIdx.x >> 3);
    const int qc = blk & 31, h = (blk >> 5) & 15, b = blk >> 9;
    const int q0 = qc * 128;
    const unsigned short* Qh = qb + (size_t)(b * NH + h) * SEQ * HDIM;
    const unsigned short* Kh = kb + (size_t)(b * NH + h) * SEQ * HDIM;
    const unsigned short* Vh = vtb + (size_t)(b * NH + h) * HDIM * SEQ;
    const int qw = q0 + wid * 16;

    bf16x8 qf0 = *(const bf16x8*)(Qh + (size_t)(qw + lr) * HDIM + lg * 8);
    bf16x8 qf1 = *(const bf16x8*)(Qh + (size_t)(qw + lr) * HDIM + 32 + lg * 8);

    f32x4 oacc[4];
    float lsum[4];
#pragma unroll
    for (int n = 0; n < 4; ++n) {
        f32x4 z = {0.f, 0.f, 0.f, 0.f};
        oacc[n] = z;
    }
#pragma unroll
    for (int r = 0; r < 4; ++r) lsum[r] = 0.f;

    int lo = q0 - 256; if (lo < 0) lo = 0;
    int hi = q0 + 384; if (hi > SEQ) hi = SEQ;

    const int srow = tid >> 3, sseg = (tid & 7) * 8;  // 64 rows x 8 x 16B

    us8 kpre = *(const us8*)(Kh + (size_t)(lo + srow) * HDIM + sseg);
    us8 vpre = *(const us8*)(Vh + (size_t)srow * SEQ + lo + sseg);

    for (int kt = lo; kt < hi; kt += 64) {
        __syncthreads();
        *(us8*)&Ks[srow][sseg] = kpre;
        *(us8*)&Vs[srow][sseg] = vpre;
        if (kt + 64 < hi) {
            kpre = *(const us8*)(Kh + (size_t)(kt + 64 + srow) * HDIM + sseg);
            vpre = *(const us8*)(Vh + (size_t)srow * SEQ + kt + 64 + sseg);
        }
        __builtin_amdgcn_sched_barrier(0);
        __syncthreads();

        f32x4 sf[4];
        __builtin_amdgcn_s_setprio(1);
#pragma unroll
        for (int n = 0; n < 4; ++n) {
            bf16x8 kf0 = *(const bf16x8*)&Ks[n * 16 + lr][lg * 8];
            bf16x8 kf1 = *(const bf16x8*)&Ks[n * 16 + lr][32 + lg * 8];
            f32x4 z = {0.f, 0.f, 0.f, 0.f};
            sf[n] = __builtin_amdgcn_mfma_f32_16x16x32_bf16(qf0, kf0, z, 0, 0, 0);
            sf[n] = __builtin_amdgcn_mfma_f32_16x16x32_bf16(qf1, kf1, sf[n], 0, 0, 0);
        }
        __builtin_amdgcn_s_setprio(0);
        const bool full = (kt >= qw - 241) && (kt + 63 <= qw + 256);
        if (!full) {
#pragma unroll
            for (int r = 0; r < 4; ++r) {
                const int qpos = qw + lg * 4 + r;
#pragma unroll
                for (int n = 0; n < 4; ++n) {
                    const int kpos = kt + n * 16 + lr;
                    if (kpos < qpos - 256 || kpos > qpos + 256) sf[n][r] = NEGM;
                }
            }
        }
#pragma unroll
        for (int n = 0; n < 4; ++n)
#pragma unroll
            for (int r = 0; r < 4; ++r) {
                const float p = __expf(sf[n][r]);
                lsum[r] += p;
                Ps[wid][lg * 4 + r][n * 16 + lr] = f2bf(p);
            }

        asm volatile("s_waitcnt lgkmcnt(0)" ::: "memory");
        __builtin_amdgcn_s_setprio(1);
#pragma unroll
        for (int ks = 0; ks < 2; ++ks) {
            bf16x8 pf = *(const bf16x8*)&Ps[wid][lr][ks * 32 + lg * 8];
#pragma unroll
            for (int n = 0; n < 4; ++n) {
                bf16x8 vf = *(const bf16x8*)&Vs[n * 16 + lr][ks * 32 + lg * 8];
                oacc[n] = __builtin_amdgcn_mfma_f32_16x16x32_bf16(pf, vf, oacc[n], 0, 0, 0);
            }
        }
        __builtin_amdgcn_s_setprio(0);
    }

#pragma unroll
    for (int d = 1; d < 16; d <<= 1)
#pragma unroll
        for (int r = 0; r < 4; ++r) lsum[r] += __shfl_xor(lsum[r], d, 64);

#pragma unroll
    for (int n = 0; n < 4; ++n)
#pragma unroll
        for (int r = 0; r < 4; ++r) {
            const int row = qw + lg * 4 + r;
            const float o = oacc[n][r] / lsum[r];
            ao[((size_t)b * SEQ + row) * DMODEL + h * HDIM + n * 16 + lr] = f2bf(o);
        }
}

extern "C" void kernel_launch(void* const* d_in, const int* in_sizes, int n_in,
                              void* d_out, int out_size, void* d_ws, size_t ws_size,
                              hipStream_t stream) {
    (void)in_sizes; (void)n_in; (void)out_size; (void)ws_size;
    const float* query = (const float*)d_in[0];
    const float* Wq = (const float*)d_in[1];
    const float* bq = (const float*)d_in[2];
    const float* Wk = (const float*)d_in[3];
    const float* bk = (const float*)d_in[4];
    const float* Wv = (const float*)d_in[5];
    const float* bv = (const float*)d_in[6];
    const float* Wo = (const float*)d_in[7];
    const float* bo = (const float*)d_in[8];
    float* out = (float*)d_out;

    char* ws = (char*)d_ws;
    unsigned short* xb   = (unsigned short*)ws;                       // 16MB (reused as ao)
    unsigned short* wcat = (unsigned short*)(ws + (16ull << 20));     // 6MB
    unsigned short* wot  = (unsigned short*)(ws + (22ull << 20));     // 2MB
    float*          bcat = (float*)(ws + (24ull << 20));              // 12KB
    unsigned short* qb   = (unsigned short*)(ws + (25ull << 20));     // 16MB
    unsigned short* kb   = (unsigned short*)(ws + (41ull << 20));     // 16MB
    unsigned short* vtb  = (unsigned short*)(ws + (57ull << 20));     // 16MB
    unsigned short* ao   = xb;

    prep_all<<<9228, 256, 0, stream>>>(Wq, Wk, Wv, Wo, query, bq, bk, bv,
                                       wcat, wot, xb, bcat);
    gemm192<<<512, 512, 0, stream>>>(xb, wcat, bcat, qb, kb, vtb);
    attn_kernel<<<1024, 512, 0, stream>>>(qb, kb, vtb, ao);
    gemm128o<<<512, 256, 0, stream>>>(ao, wot, bo, out);
}